// Round 5
// baseline (517.904 us; speedup 1.0000x reference)
//
#include <hip/hip_runtime.h>
#include <math.h>

#define NC 6
#define NS 500
#define HWD 768
#define NP (HWD*HWD)
#define EPSF 1e-5f
#define NITER 5

// ---------------------------------------------------------------------------
// mix_kernel: M = compat @ (spatial_w + bilateral_w)   (6x6, one tiny block)
// ---------------------------------------------------------------------------
__global__ void mix_kernel(const float* __restrict__ sw, const float* __restrict__ bw,
                           const float* __restrict__ cm, float* __restrict__ M) {
    int i = threadIdx.x;
    if (i < NC * NC) {
        int c = i / NC, k = i % NC;
        float acc = 0.f;
        #pragma unroll
        for (int j = 0; j < NC; j++) acc += cm[c * NC + j] * (sw[j * NC + k] + bw[j * NC + k]);
        M[i] = acc;
    }
}

// ---------------------------------------------------------------------------
// prep_kernel: q[c,p] = unaries[p*C+c];  seg[p] = sp_map[(p%768)*768 + p/768]
// ---------------------------------------------------------------------------
__global__ __launch_bounds__(256) void prep_kernel(const float* __restrict__ unaries,
                                                   const int* __restrict__ sp_map,
                                                   float* __restrict__ q,
                                                   int* __restrict__ seg) {
    int p = blockIdx.x * blockDim.x + threadIdx.x;
    if (p >= NP) return;
    int h = p / HWD;
    int w = p - h * HWD;
    seg[p] = sp_map[w * HWD + h];
    #pragma unroll
    for (int c = 0; c < NC; c++) q[c * NP + p] = unaries[p * NC + c];
}

// ---------------------------------------------------------------------------
// iter_a: softmax(q) -> sm;  accumulate segment log-sum tables (LDS-staged)
// grid-size independent: per-block LDS tables merged via global atomicAdd
// ---------------------------------------------------------------------------
__global__ __launch_bounds__(256) void iter_a(const float* __restrict__ q,
                                              float* __restrict__ sm,
                                              const int* __restrict__ seg,
                                              float* __restrict__ Bsp,
                                              float* __restrict__ Bcont) {
    __shared__ float lsp[NS * NC];
    __shared__ float lco[NS * NC];
    for (int i = threadIdx.x; i < NS * NC; i += blockDim.x) { lsp[i] = 0.f; lco[i] = 0.f; }
    __syncthreads();

    int chunk = (NP + gridDim.x - 1) / gridDim.x;
    int start = blockIdx.x * chunk;
    int end = min(NP, start + chunk);

    for (int p = start + (int)threadIdx.x; p < end; p += blockDim.x) {
        float v[NC];
        float m = -3.402823466e+38f;
        #pragma unroll
        for (int c = 0; c < NC; c++) { v[c] = q[c * NP + p]; m = fmaxf(m, v[c]); }
        float s = 0.f;
        #pragma unroll
        for (int c = 0; c < NC; c++) { v[c] = expf(v[c] - m); s += v[c]; }
        float inv = 1.f / s;
        #pragma unroll
        for (int c = 0; c < NC; c++) { v[c] *= inv; sm[c * NP + p] = v[c]; }

        int sg = seg[p];
        if (sg >= 0 && sg < NS) {
            float mx = v[0];
            #pragma unroll
            for (int c = 1; c < NC; c++) mx = fmaxf(mx, v[c]);
            float maxq = mx + EPSF;
            int base = sg * NC;
            #pragma unroll
            for (int c = 0; c < NC; c++) {
                atomicAdd(&lsp[base + c], logf(v[c] + EPSF));
                float a = v[c] + EPSF + maxq - ((v[c] == mx) ? v[c] : 0.f);
                atomicAdd(&lco[base + c], logf(a));
            }
        }
    }
    __syncthreads();
    for (int i = threadIdx.x; i < NS * NC; i += blockDim.x) {
        atomicAdd(&Bsp[i], lsp[i]);
        atomicAdd(&Bcont[i], lco[i]);
    }
}

// ---------------------------------------------------------------------------
// iter_b: per-pixel update  q = u - M@sm - (sp_update + cont_update)
// ---------------------------------------------------------------------------
__global__ __launch_bounds__(256) void iter_b(const float* __restrict__ unaries,
                                              const float* __restrict__ sm,
                                              const int* __restrict__ seg,
                                              const float* __restrict__ Bsp,
                                              const float* __restrict__ Bcont,
                                              const float* __restrict__ low_w,
                                              const float* __restrict__ high_w,
                                              const float* __restrict__ M,
                                              float* __restrict__ q,
                                              float* __restrict__ out,
                                              int writeOut) {
    __shared__ float sM[NC * NC];
    __shared__ float slw[2 * NC];
    __shared__ float shw[2];
    if (threadIdx.x < NC * NC) sM[threadIdx.x] = M[threadIdx.x];
    if (threadIdx.x < 2 * NC) slw[threadIdx.x] = low_w[threadIdx.x];
    if (threadIdx.x < 2) shw[threadIdx.x] = high_w[threadIdx.x];
    __syncthreads();

    int stride = gridDim.x * blockDim.x;
    for (int p = blockIdx.x * blockDim.x + threadIdx.x; p < NP; p += stride) {
        float v[NC];
        #pragma unroll
        for (int c = 0; c < NC; c++) v[c] = sm[c * NP + p];

        int sg = seg[p];
        bool inr = (sg >= 0 && sg < NS);
        int sc = inr ? sg : (sg < 0 ? 0 : NS - 1);
        float fin = inr ? 1.f : 0.f;

        float mx = v[0];
        #pragma unroll
        for (int c = 1; c < NC; c++) mx = fmaxf(mx, v[c]);
        float maxq = mx + EPSF;

        float cont[NC];
        #pragma unroll
        for (int c = 0; c < NC; c++) {
            float psp = Bsp[sc * NC + c] * fin;
            float pio = Bcont[sc * NC + c] * fin;
            float a = v[c] + EPSF + maxq - ((v[c] == mx) ? v[c] : 0.f);
            float qvs = a * fin;
            qvs += (qvs == 0.f) ? 1.f : 0.f;
            float qmod = v[c] + ((v[c] == 0.f) ? 1.f : 0.f);
            float ftsp = expf(psp - logf(qmod + EPSF));
            float spu = slw[c] * ftsp + shw[0] * (1.f - ftsp);
            float ftc = expf(pio - logf(qvs + EPSF));
            float cu = slw[NC + c] * ftc + shw[1] * (1.f - ftc);
            cont[c] = spu + cu;
        }
        #pragma unroll
        for (int c = 0; c < NC; c++) {
            float pw = 0.f;
            #pragma unroll
            for (int k = 0; k < NC; k++) pw += sM[c * NC + k] * v[k];
            float qn = unaries[p * NC + c] - pw - cont[c];
            q[c * NP + p] = qn;
            if (writeOut) out[p * NC + c] = qn;
        }
    }
}

extern "C" void kernel_launch(void* const* d_in, const int* in_sizes, int n_in,
                              void* d_out, int out_size, void* d_ws, size_t ws_size,
                              hipStream_t stream) {
    const float* unaries = (const float*)d_in[0];
    // d_in[1] = rgb (unused: high_dim_filter replaced by identity)
    const int* sp_map   = (const int*)d_in[2];
    const float* sw     = (const float*)d_in[3];
    const float* bw     = (const float*)d_in[4];
    const float* cm     = (const float*)d_in[5];
    const float* lw     = (const float*)d_in[6];
    const float* hw     = (const float*)d_in[7];
    float* out = (float*)d_out;

    float* q    = (float*)d_ws;            // NC*NP floats
    float* sm   = q + (size_t)NC * NP;     // NC*NP floats
    int*   seg  = (int*)(sm + (size_t)NC * NP);   // NP ints
    float* Bsp  = (float*)(seg + NP);      // NS*NC floats
    float* Bcont= Bsp + NS * NC;           // NS*NC floats (contiguous with Bsp)
    float* M    = Bcont + NS * NC;         // NC*NC floats

    mix_kernel<<<1, 64, 0, stream>>>(sw, bw, cm, M);
    prep_kernel<<<(NP + 255) / 256, 256, 0, stream>>>(unaries, sp_map, q, seg);

    for (int it = 0; it < NITER; it++) {
        hipMemsetAsync(Bsp, 0, 2 * NS * NC * sizeof(float), stream);
        iter_a<<<1024, 256, 0, stream>>>(q, sm, seg, Bsp, Bcont);   // 4 blocks/CU for TLP
        iter_b<<<2048, 256, 0, stream>>>(unaries, sm, seg, Bsp, Bcont, lw, hw, M,
                                         q, out, (it == NITER - 1) ? 1 : 0);
    }
}

// Round 6
// 402.072 us; speedup vs baseline: 1.2881x; 1.2881x over previous
//
#include <hip/hip_runtime.h>
#include <math.h>

#define NC 6
#define NS 500
#define HWD 768
#define NP (HWD*HWD)
#define EPSF 1e-5f
#define NITER 5
#define TBL (NS*NC)          // 3000 entries per table
#define ABLK 512             // iter_a grid size (partial tables)
#define RCHUNK (ABLK/16)     // rows per reduce block (16 y-chunks)

// ---------------------------------------------------------------------------
// mix_kernel: M = compat @ (spatial_w + bilateral_w)   (6x6, one tiny block)
// ---------------------------------------------------------------------------
__global__ void mix_kernel(const float* __restrict__ sw, const float* __restrict__ bw,
                           const float* __restrict__ cm, float* __restrict__ M) {
    int i = threadIdx.x;
    if (i < NC * NC) {
        int c = i / NC, k = i % NC;
        float acc = 0.f;
        #pragma unroll
        for (int j = 0; j < NC; j++) acc += cm[c * NC + j] * (sw[j * NC + k] + bw[j * NC + k]);
        M[i] = acc;
    }
}

// ---------------------------------------------------------------------------
// prep_kernel: q[c,p] = unaries[p*C+c];  seg[p] = sp_map[(p%768)*768 + p/768]
// ---------------------------------------------------------------------------
__global__ __launch_bounds__(256) void prep_kernel(const float* __restrict__ unaries,
                                                   const int* __restrict__ sp_map,
                                                   float* __restrict__ q,
                                                   int* __restrict__ seg) {
    int p = blockIdx.x * blockDim.x + threadIdx.x;
    if (p >= NP) return;
    int h = p / HWD;
    int w = p - h * HWD;
    seg[p] = sp_map[w * HWD + h];
    #pragma unroll
    for (int c = 0; c < NC; c++) q[c * NP + p] = unaries[p * NC + c];
}

// ---------------------------------------------------------------------------
// iter_a: softmax(q) -> sm;  per-block segment log-sum tables -> partials
// (plain coalesced stores; NO contended global atomics)
// ---------------------------------------------------------------------------
__global__ __launch_bounds__(256) void iter_a(const float* __restrict__ q,
                                              float* __restrict__ sm,
                                              const int* __restrict__ seg,
                                              float* __restrict__ partials) {
    __shared__ float lsp[TBL];
    __shared__ float lco[TBL];
    for (int i = threadIdx.x; i < TBL; i += blockDim.x) { lsp[i] = 0.f; lco[i] = 0.f; }
    __syncthreads();

    int chunk = (NP + gridDim.x - 1) / gridDim.x;
    int start = blockIdx.x * chunk;
    int end = min(NP, start + chunk);

    for (int p = start + (int)threadIdx.x; p < end; p += blockDim.x) {
        float v[NC];
        float m = -3.402823466e+38f;
        #pragma unroll
        for (int c = 0; c < NC; c++) { v[c] = q[c * NP + p]; m = fmaxf(m, v[c]); }
        float s = 0.f;
        #pragma unroll
        for (int c = 0; c < NC; c++) { v[c] = expf(v[c] - m); s += v[c]; }
        float inv = 1.f / s;
        #pragma unroll
        for (int c = 0; c < NC; c++) { v[c] *= inv; sm[c * NP + p] = v[c]; }

        int sg = seg[p];
        if (sg >= 0 && sg < NS) {
            float mx = v[0];
            #pragma unroll
            for (int c = 1; c < NC; c++) mx = fmaxf(mx, v[c]);
            float maxq = mx + EPSF;
            int base = sg * NC;
            #pragma unroll
            for (int c = 0; c < NC; c++) {
                atomicAdd(&lsp[base + c], logf(v[c] + EPSF));
                float a = v[c] + EPSF + maxq - ((v[c] == mx) ? v[c] : 0.f);
                atomicAdd(&lco[base + c], logf(a));
            }
        }
    }
    __syncthreads();
    float* pout = partials + (size_t)blockIdx.x * (2 * TBL);
    for (int i = threadIdx.x; i < TBL; i += blockDim.x) {
        pout[i] = lsp[i];
        pout[TBL + i] = lco[i];
    }
}

// ---------------------------------------------------------------------------
// reduce_kernel: B[i] = sum_b partials[b][i]  (16-way atomic contention only)
// grid: (ceil(2*TBL/256), 16)
// ---------------------------------------------------------------------------
__global__ __launch_bounds__(256) void reduce_kernel(const float* __restrict__ partials,
                                                     float* __restrict__ B) {
    int i = blockIdx.x * blockDim.x + threadIdx.x;
    if (i >= 2 * TBL) return;
    int r0 = blockIdx.y * RCHUNK;
    float s = 0.f;
    #pragma unroll 4
    for (int r = r0; r < r0 + RCHUNK; r++)
        s += partials[(size_t)r * (2 * TBL) + i];
    atomicAdd(&B[i], s);
}

// ---------------------------------------------------------------------------
// iter_b: per-pixel update  q = u - M@sm - (sp_update + cont_update)
// ---------------------------------------------------------------------------
__global__ __launch_bounds__(256) void iter_b(const float* __restrict__ unaries,
                                              const float* __restrict__ sm,
                                              const int* __restrict__ seg,
                                              const float* __restrict__ Bsp,
                                              const float* __restrict__ Bcont,
                                              const float* __restrict__ low_w,
                                              const float* __restrict__ high_w,
                                              const float* __restrict__ M,
                                              float* __restrict__ q,
                                              float* __restrict__ out,
                                              int writeOut) {
    __shared__ float sM[NC * NC];
    __shared__ float slw[2 * NC];
    __shared__ float shw[2];
    if (threadIdx.x < NC * NC) sM[threadIdx.x] = M[threadIdx.x];
    if (threadIdx.x < 2 * NC) slw[threadIdx.x] = low_w[threadIdx.x];
    if (threadIdx.x < 2) shw[threadIdx.x] = high_w[threadIdx.x];
    __syncthreads();

    int stride = gridDim.x * blockDim.x;
    for (int p = blockIdx.x * blockDim.x + threadIdx.x; p < NP; p += stride) {
        float v[NC];
        #pragma unroll
        for (int c = 0; c < NC; c++) v[c] = sm[c * NP + p];

        int sg = seg[p];
        bool inr = (sg >= 0 && sg < NS);
        int sc = inr ? sg : (sg < 0 ? 0 : NS - 1);
        float fin = inr ? 1.f : 0.f;

        float mx = v[0];
        #pragma unroll
        for (int c = 1; c < NC; c++) mx = fmaxf(mx, v[c]);
        float maxq = mx + EPSF;

        float cont[NC];
        #pragma unroll
        for (int c = 0; c < NC; c++) {
            float psp = Bsp[sc * NC + c] * fin;
            float pio = Bcont[sc * NC + c] * fin;
            float a = v[c] + EPSF + maxq - ((v[c] == mx) ? v[c] : 0.f);
            float qvs = a * fin;
            qvs += (qvs == 0.f) ? 1.f : 0.f;
            float qmod = v[c] + ((v[c] == 0.f) ? 1.f : 0.f);
            float ftsp = expf(psp - logf(qmod + EPSF));
            float spu = slw[c] * ftsp + shw[0] * (1.f - ftsp);
            float ftc = expf(pio - logf(qvs + EPSF));
            float cu = slw[NC + c] * ftc + shw[1] * (1.f - ftc);
            cont[c] = spu + cu;
        }
        #pragma unroll
        for (int c = 0; c < NC; c++) {
            float pw = 0.f;
            #pragma unroll
            for (int k = 0; k < NC; k++) pw += sM[c * NC + k] * v[k];
            float qn = unaries[p * NC + c] - pw - cont[c];
            q[c * NP + p] = qn;
            if (writeOut) out[p * NC + c] = qn;
        }
    }
}

extern "C" void kernel_launch(void* const* d_in, const int* in_sizes, int n_in,
                              void* d_out, int out_size, void* d_ws, size_t ws_size,
                              hipStream_t stream) {
    const float* unaries = (const float*)d_in[0];
    // d_in[1] = rgb (unused: high_dim_filter replaced by identity)
    const int* sp_map   = (const int*)d_in[2];
    const float* sw     = (const float*)d_in[3];
    const float* bw     = (const float*)d_in[4];
    const float* cm     = (const float*)d_in[5];
    const float* lw     = (const float*)d_in[6];
    const float* hw     = (const float*)d_in[7];
    float* out = (float*)d_out;

    float* q       = (float*)d_ws;                     // NC*NP floats
    float* sm      = q + (size_t)NC * NP;              // NC*NP floats
    int*   seg     = (int*)(sm + (size_t)NC * NP);     // NP ints
    float* Bsp     = (float*)(seg + NP);               // TBL floats
    float* Bcont   = Bsp + TBL;                        // TBL floats (contiguous)
    float* M       = Bcont + TBL;                      // NC*NC floats
    float* partials= M + NC * NC;                      // ABLK * 2*TBL floats (12.3 MB)

    mix_kernel<<<1, 64, 0, stream>>>(sw, bw, cm, M);
    prep_kernel<<<(NP + 255) / 256, 256, 0, stream>>>(unaries, sp_map, q, seg);

    dim3 rgrid((2 * TBL + 255) / 256, 16);
    for (int it = 0; it < NITER; it++) {
        hipMemsetAsync(Bsp, 0, 2 * TBL * sizeof(float), stream);
        iter_a<<<ABLK, 256, 0, stream>>>(q, sm, seg, partials);
        reduce_kernel<<<rgrid, 256, 0, stream>>>(partials, Bsp);
        iter_b<<<2048, 256, 0, stream>>>(unaries, sm, seg, Bsp, Bcont, lw, hw, M,
                                         q, out, (it == NITER - 1) ? 1 : 0);
    }
}